// Round 1
// 225.105 us; speedup vs baseline: 1.0667x; 1.0667x over previous
//
#include <hip/hip_runtime.h>
#include <stdint.h>

#define CIN  256
#define CR   32
#define COUT 560   // 32 singles + 528 upper-tri pairs

// ---------------------------------------------------------------------------
// K1: z = relu(bn(conv1x1(x))), fp32.  Grid 256 x 512thr.
// Block = 256-px slab (b, p0). Wave og=tid>>6 (wave-uniform) owns out-ch
// 4*og..4*og+3; lane q=tid&63 owns pixel quad p0+4q..p0+4q+3.
// All x traffic is float4 (1KB per wave-instr); weights go through the
// scalar path (uniform og -> s_load / constant cache).
// ---------------------------------------------------------------------------
__global__ __launch_bounds__(512) void k_conv1x1(
    const float* __restrict__ x,
    const float* __restrict__ wr,
    const float* __restrict__ gamma,
    const float* __restrict__ beta,
    const float* __restrict__ mean,
    const float* __restrict__ var,
    float* __restrict__ z)
{
    const int tid = threadIdx.x;
    const int og  = __builtin_amdgcn_readfirstlane(tid >> 6);   // 0..7
    const int q   = tid & 63;                                   // px quad
    const int blk = blockIdx.x;                                 // 0..255
    const int b   = blk >> 4;
    const int p0  = (blk & 15) << 8;                            // 256-px slab

    const float* xb = x + ((((size_t)b) * CIN) << 12) + p0 + (q << 2);
    const float* wp = wr + og * 4 * CIN;

    float4 a0 = {0.f,0.f,0.f,0.f};
    float4 a1 = {0.f,0.f,0.f,0.f};
    float4 a2 = {0.f,0.f,0.f,0.f};
    float4 a3 = {0.f,0.f,0.f,0.f};

    #pragma unroll 2
    for (int cc = 0; cc < 16; ++cc) {
        float4 xv[16];
        #pragma unroll
        for (int k = 0; k < 16; ++k)
            xv[k] = *(const float4*)(xb + ((size_t)(cc * 16 + k) << 12));
        #pragma unroll
        for (int k = 0; k < 16; ++k) {
            const int ic = cc * 16 + k;
            const float w0 = wp[           ic];
            const float w1 = wp[    CIN  + ic];
            const float w2 = wp[2 * CIN  + ic];
            const float w3 = wp[3 * CIN  + ic];
            a0.x = fmaf(xv[k].x, w0, a0.x);
            a0.y = fmaf(xv[k].y, w0, a0.y);
            a0.z = fmaf(xv[k].z, w0, a0.z);
            a0.w = fmaf(xv[k].w, w0, a0.w);
            a1.x = fmaf(xv[k].x, w1, a1.x);
            a1.y = fmaf(xv[k].y, w1, a1.y);
            a1.z = fmaf(xv[k].z, w1, a1.z);
            a1.w = fmaf(xv[k].w, w1, a1.w);
            a2.x = fmaf(xv[k].x, w2, a2.x);
            a2.y = fmaf(xv[k].y, w2, a2.y);
            a2.z = fmaf(xv[k].z, w2, a2.z);
            a2.w = fmaf(xv[k].w, w2, a2.w);
            a3.x = fmaf(xv[k].x, w3, a3.x);
            a3.y = fmaf(xv[k].y, w3, a3.y);
            a3.z = fmaf(xv[k].z, w3, a3.z);
            a3.w = fmaf(xv[k].w, w3, a3.w);
        }
    }

    float4* zq = (float4*)(z + (((size_t)b * CR) << 12) + p0 + (q << 2));
    #pragma unroll
    for (int o = 0; o < 4; ++o) {
        const int oc = og * 4 + o;
        const float inv = gamma[oc] / sqrtf(var[oc] + 1e-5f);
        const float bia = beta[oc] - mean[oc] * inv;
        const float4 a = (o == 0) ? a0 : (o == 1) ? a1 : (o == 2) ? a2 : a3;
        float4 r;
        r.x = fmaxf(fmaf(a.x, inv, bia), 0.f);
        r.y = fmaxf(fmaf(a.y, inv, bia), 0.f);
        r.z = fmaxf(fmaf(a.z, inv, bia), 0.f);
        r.w = fmaxf(fmaf(a.w, inv, bia), 0.f);
        zq[(size_t)oc << 10] = r;                  // plane stride 4096 floats
    }
}

// ---------------------------------------------------------------------------
// K2: depthwise 3x3 * scale, dual L2-norm, 560 fp32 planes. Grid 256 x 256thr.
// Block = 4-row slab (256 px). Lane: r=lane>>4 (row), cq=lane&15 (col quad).
// cg=tid>>6 (wave-uniform) owns 8 STRIDE-4 channels {cg, cg+4, ..., cg+28}:
// the j-outer pair loop is then balanced (120..144 pairs/thread).
// tw stays in registers (no twl LDS); znl staged in LDS as float4.
// All global/LDS traffic is b128; all weight/scale reads wave-uniform.
// ---------------------------------------------------------------------------
__global__ __launch_bounds__(256) void k_twist(
    const float* __restrict__ z,
    const float* __restrict__ dww,
    const float* __restrict__ scl,
    float* __restrict__ out)
{
    __shared__ float4 znl4[CR][64];   // 32 KB  normalized z, [ch][lane(quad)]
    __shared__ float4 ps1[4][64];     //  4 KB  per-cg partial |z|^2 per px
    __shared__ float4 ps2[4][64];     //  4 KB  per-cg partial |tw|^2 per px

    const int tid  = threadIdx.x;
    const int cg   = __builtin_amdgcn_readfirstlane(tid >> 6);  // 0..3
    const int lane = tid & 63;
    const int r    = lane >> 4;        // row within slab
    const int cq   = lane & 15;        // col quad
    const int blk  = blockIdx.x;       // 0..255
    const int b    = blk >> 4;
    const int h0   = (blk & 15) << 2;  // slab base row
    const int hh   = h0 + r;           // this thread's row

    const float* zb = z + (((size_t)b * CR) << 12);

    float4 zc[8], tw[8];
    float4 s1 = {0.f,0.f,0.f,0.f};
    float4 s2 = {0.f,0.f,0.f,0.f};

    #pragma unroll
    for (int k = 0; k < 8; ++k) {
        const int c = cg + 4 * k;                     // wave-uniform
        const float* zp = zb + ((size_t)c << 12);
        float4 acc = {0.f,0.f,0.f,0.f};
        float4 ctr = {0.f,0.f,0.f,0.f};
        #pragma unroll
        for (int dy = 0; dy < 3; ++dy) {
            const int hy = hh + dy - 1;
            const bool rok = ((unsigned)hy) < 64u;
            const float* zr = zp + (hy << 6);
            float4 M  = {0.f,0.f,0.f,0.f};
            float4 L4 = {0.f,0.f,0.f,0.f};
            float4 R4 = {0.f,0.f,0.f,0.f};
            if (rok) {
                M = *(const float4*)(zr + (cq << 2));
                if (cq > 0)  L4 = *(const float4*)(zr + (cq << 2) - 4);
                if (cq < 15) R4 = *(const float4*)(zr + (cq << 2) + 4);
            }
            const float w0 = dww[c * 9 + dy * 3 + 0];
            const float w1 = dww[c * 9 + dy * 3 + 1];
            const float w2 = dww[c * 9 + dy * 3 + 2];
            // 6-wide window: {L4.w, M.x, M.y, M.z, M.w, R4.x}
            acc.x = fmaf(w0, L4.w, fmaf(w1, M.x, fmaf(w2, M.y, acc.x)));
            acc.y = fmaf(w0, M.x,  fmaf(w1, M.y, fmaf(w2, M.z, acc.y)));
            acc.z = fmaf(w0, M.y,  fmaf(w1, M.z, fmaf(w2, M.w, acc.z)));
            acc.w = fmaf(w0, M.z,  fmaf(w1, M.w, fmaf(w2, R4.x, acc.w)));
            if (dy == 1) ctr = M;
        }
        const float s = scl[c];
        float4 t;
        t.x = acc.x * s;  t.y = acc.y * s;  t.z = acc.z * s;  t.w = acc.w * s;
        zc[k] = ctr;  tw[k] = t;
        s1.x = fmaf(ctr.x, ctr.x, s1.x);  s1.y = fmaf(ctr.y, ctr.y, s1.y);
        s1.z = fmaf(ctr.z, ctr.z, s1.z);  s1.w = fmaf(ctr.w, ctr.w, s1.w);
        s2.x = fmaf(t.x, t.x, s2.x);      s2.y = fmaf(t.y, t.y, s2.y);
        s2.z = fmaf(t.z, t.z, s2.z);      s2.w = fmaf(t.w, t.w, s2.w);
    }

    ps1[cg][lane] = s1;
    ps2[cg][lane] = s2;
    __syncthreads();

    float4 t1, t2;
    {
        const float4 u0 = ps1[0][lane], u1 = ps1[1][lane],
                     u2 = ps1[2][lane], u3 = ps1[3][lane];
        t1.x = u0.x + u1.x + u2.x + u3.x;  t1.y = u0.y + u1.y + u2.y + u3.y;
        t1.z = u0.z + u1.z + u2.z + u3.z;  t1.w = u0.w + u1.w + u2.w + u3.w;
        const float4 v0 = ps2[0][lane], v1 = ps2[1][lane],
                     v2 = ps2[2][lane], v3 = ps2[3][lane];
        t2.x = v0.x + v1.x + v2.x + v3.x;  t2.y = v0.y + v1.y + v2.y + v3.y;
        t2.z = v0.z + v1.z + v2.z + v3.z;  t2.w = v0.w + v1.w + v2.w + v3.w;
    }
    float4 rn1, rn2;
    rn1.x = 1.0f / fmaxf(sqrtf(t1.x), 1e-6f);
    rn1.y = 1.0f / fmaxf(sqrtf(t1.y), 1e-6f);
    rn1.z = 1.0f / fmaxf(sqrtf(t1.z), 1e-6f);
    rn1.w = 1.0f / fmaxf(sqrtf(t1.w), 1e-6f);
    rn2.x = 1.0f / fmaxf(sqrtf(t2.x), 1e-6f);
    rn2.y = 1.0f / fmaxf(sqrtf(t2.y), 1e-6f);
    rn2.z = 1.0f / fmaxf(sqrtf(t2.z), 1e-6f);
    rn2.w = 1.0f / fmaxf(sqrtf(t2.w), 1e-6f);

    float4* outq = (float4*)(out + (((size_t)b * COUT) << 12) + (hh << 6)) + cq;
    // plane stride in float4 units = 1024

    // singles (planes 0..31 = z_norm) + stage znl; normalize tw in-register
    #pragma unroll
    for (int k = 0; k < 8; ++k) {
        const int c = cg + 4 * k;
        float4 zn;
        zn.x = zc[k].x * rn1.x;  zn.y = zc[k].y * rn1.y;
        zn.z = zc[k].z * rn1.z;  zn.w = zc[k].w * rn1.w;
        outq[(size_t)c << 10] = zn;
        znl4[c][lane] = zn;
        tw[k].x *= rn2.x;  tw[k].y *= rn2.y;
        tw[k].z *= rn2.z;  tw[k].w *= rn2.w;
    }
    __syncthreads();

    // pairs: plane P(i,j) = 32 + (32i - i(i-1)/2) + (j-i); delta over i: 31-i.
    // j-outer with j = this thread's channels -> tw[j] never touches LDS.
    #pragma unroll
    for (int k = 0; k < 8; ++k) {
        const int j = cg + 4 * k;                 // wave-uniform
        const float4 t = tw[k];
        int P = 32 + j;                           // i = 0 entry
        for (int i = 0; i <= j; ++i) {
            const float4 zi = znl4[i][lane];
            float4 v;
            v.x = zi.x * t.x;  v.y = zi.y * t.y;
            v.z = zi.z * t.z;  v.w = zi.w * t.w;
            outq[(size_t)P << 10] = v;
            P += 31 - i;
        }
    }
}

extern "C" void kernel_launch(void* const* d_in, const int* in_sizes, int n_in,
                              void* d_out, int out_size, void* d_ws, size_t ws_size,
                              hipStream_t stream) {
    const float* x     = (const float*)d_in[0];
    const float* wr    = (const float*)d_in[1];
    const float* gamma = (const float*)d_in[2];
    const float* beta  = (const float*)d_in[3];
    const float* mean  = (const float*)d_in[4];
    const float* var   = (const float*)d_in[5];
    const float* dww   = (const float*)d_in[6];
    const float* scl   = (const float*)d_in[7];
    float* z   = (float*)d_ws;                    // 8 MB fp32 scratch
    float* out = (float*)d_out;

    hipLaunchKernelGGL(k_conv1x1, dim3(256), dim3(512), 0, stream,
                       x, wr, gamma, beta, mean, var, z);
    hipLaunchKernelGGL(k_twist, dim3(256), dim3(256), 0, stream,
                       z, dww, scl, out);
}